// Round 1
// baseline (2022.310 us; speedup 1.0000x reference)
//
#include <hip/hip_runtime.h>

// Problem constants (fixed by the reference)
#define BTOT 4096
#define TB   512      // T
#define BD   8        // D (input dim)
#define BSL  16       // batch rows per block
#define K0   96       // layer0 A: [h0(64) | x(8) | pad(24)]
#define K1   128      // layer1 A: [h0_t(64) | h1_prev(64)]

typedef __attribute__((ext_vector_type(8))) short  short8;  // 8 bf16 = 4 VGPR (MFMA A/B frag)
typedef __attribute__((ext_vector_type(4))) float  f32x4;   // MFMA C/D frag

static __device__ __forceinline__ unsigned short f2bf(float f) {
    unsigned u = __float_as_uint(f);
    u += 0x7fffu + ((u >> 16) & 1u);        // round-to-nearest-even
    return (unsigned short)(u >> 16);
}
static __device__ __forceinline__ float bf2f(unsigned short h) {
    return __uint_as_float(((unsigned)h) << 16);
}
// sigmoid(x) = 1/(1+2^(-x*log2e));  exp2 overflow -> inf -> rcp -> 0 (safe, NaN-free)
static __device__ __forceinline__ float sigm(float x) {
    float e = __builtin_amdgcn_exp2f(-1.44269504f * x);
    return __builtin_amdgcn_rcpf(1.0f + e);
}
// tanh(x) = 1 - 2/(1+2^(2x*log2e))
static __device__ __forceinline__ float tanh_(float x) {
    float e = __builtin_amdgcn_exp2f(2.88539008f * x);
    return 1.0f - 2.0f * __builtin_amdgcn_rcpf(1.0f + e);
}

__global__ __launch_bounds__(512, 2) void lstm2_fused(
    const float* __restrict__ x,
    const float* __restrict__ Wih0, const float* __restrict__ Whh0,
    const float* __restrict__ bih0, const float* __restrict__ bhh0,
    const float* __restrict__ Wih1, const float* __restrict__ Whh1,
    const float* __restrict__ bih1, const float* __restrict__ bhh1,
    const float* __restrict__ Wfc,  const float* __restrict__ bfc,
    float* __restrict__ out)
{
    // Double-buffered (by step parity) bf16 activation tiles.
    __shared__ __align__(16) unsigned short A0[2][BSL][K0];
    __shared__ __align__(16) unsigned short A1[2][BSL][K1];

    const int tid  = threadIdx.x;
    const int wid  = tid >> 6;
    const int lane = tid & 63;
    const int q    = lane >> 4;          // quad (k-chunk for A/B frags, row group for C/D)
    const int ln   = lane & 15;          // A row (m) / B col (n) / C col
    const int rb   = blockIdx.x * BSL;   // first batch row of this block

    const bool L1w = (wid >= 4);         // waves 4..7 = layer 1; waves 0..3 = layer 0
    const int  g   = L1w ? (wid - 4) : wid;
    const int  jc  = g * 16 + ln;        // hidden col (0..63) this lane owns for all 4 gates

    // ---- Weight (B-operand) fragments -> registers, bf16, once ----
    // B frag layout: lane holds B[k = q*8 + j][n = ln] for j=0..7 within each k-iter of 32.
    short8 Bf[4][4];                     // [gate][k_iter]; L0 uses k_iter 0..2
    for (int G = 0; G < 4; ++G) {
        const int n  = G * 64 + jc;      // gate output column (i,f,g,o blocks of 64)
        const int nk = L1w ? 4 : 3;
        for (int ki = 0; ki < nk; ++ki) {
            union { unsigned short u[8]; short8 v; } t;
            #pragma unroll
            for (int j = 0; j < 8; ++j) {
                const int k = ki * 32 + q * 8 + j;
                float w;
                if (!L1w) {
                    if (k < 64)      w = Whh0[n * 64 + k];          // recurrent
                    else if (k < 72) w = Wih0[n * 8 + (k - 64)];    // input proj (D=8)
                    else             w = 0.0f;                      // pad
                } else {
                    if (k < 64)      w = Wih1[n * 64 + k];          // from h0_t
                    else             w = Whh1[n * 64 + (k - 64)];   // recurrent
                }
                t.u[j] = f2bf(w);
            }
            Bf[G][ki] = t.v;
        }
    }
    float bias[4];
    #pragma unroll
    for (int G = 0; G < 4; ++G) {
        const int n = G * 64 + jc;
        bias[G] = L1w ? (bih1[n] + bhh1[n]) : (bih0[n] + bhh0[n]);
    }

    // ---- Zero LDS (h0_{-1}=0, h1_{-1}=0, K-pad regions must be exactly 0.0) ----
    {
        unsigned short* p0 = &A0[0][0][0];
        for (int i = tid; i < 2 * BSL * K0; i += 512) p0[i] = 0;
        unsigned short* p1 = &A1[0][0][0];
        for (int i = tid; i < 2 * BSL * K1; i += 512) p1[i] = 0;
    }
    __syncthreads();
    // ---- x_0 -> A0[0] x-region ----
    if (!L1w && lane < 8) {
        const int xrow = g * 4 + (lane >> 1), xh = lane & 1;
        const float4 v = *(const float4*)(x + ((size_t)(rb + xrow) * TB) * BD + xh * 4);
        unsigned long long pk =
            (unsigned long long)f2bf(v.x)        |
            ((unsigned long long)f2bf(v.y) << 16) |
            ((unsigned long long)f2bf(v.z) << 32) |
            ((unsigned long long)f2bf(v.w) << 48);
        *(unsigned long long*)&A0[0][xrow][64 + xh * 4] = pk;
    }
    __syncthreads();

    float cc[4] = {0.f, 0.f, 0.f, 0.f};  // fp32 cell state, never rounded

    // Pipeline: interval `it`: L0 computes step t=it, L1 computes step t1=it-1.
    for (int it = 0; it <= TB; ++it) {
        if (!L1w) {
            const int t = it;
            if (t < TB) {
                // Prefetch x_{t+1} early (hidden behind MFMA+gates)
                float4 xv;
                const bool dox = (lane < 8) && (t + 1 < TB);
                const int xrow = g * 4 + (lane >> 1), xh = lane & 1;
                if (dox)
                    xv = *(const float4*)(x + ((size_t)(rb + xrow) * TB + (t + 1)) * BD + xh * 4);

                const unsigned short* Ar = &A0[t & 1][ln][0];
                const short8 a0 = *(const short8*)(Ar + 0 * 32 + q * 8);
                const short8 a1 = *(const short8*)(Ar + 1 * 32 + q * 8);
                const short8 a2 = *(const short8*)(Ar + 2 * 32 + q * 8);

                f32x4 ai = {0.f,0.f,0.f,0.f}, af = ai, ag = ai, ao = ai;
                ai = __builtin_amdgcn_mfma_f32_16x16x32_bf16(a0, Bf[0][0], ai, 0, 0, 0);
                af = __builtin_amdgcn_mfma_f32_16x16x32_bf16(a0, Bf[1][0], af, 0, 0, 0);
                ag = __builtin_amdgcn_mfma_f32_16x16x32_bf16(a0, Bf[2][0], ag, 0, 0, 0);
                ao = __builtin_amdgcn_mfma_f32_16x16x32_bf16(a0, Bf[3][0], ao, 0, 0, 0);
                ai = __builtin_amdgcn_mfma_f32_16x16x32_bf16(a1, Bf[0][1], ai, 0, 0, 0);
                af = __builtin_amdgcn_mfma_f32_16x16x32_bf16(a1, Bf[1][1], af, 0, 0, 0);
                ag = __builtin_amdgcn_mfma_f32_16x16x32_bf16(a1, Bf[2][1], ag, 0, 0, 0);
                ao = __builtin_amdgcn_mfma_f32_16x16x32_bf16(a1, Bf[3][1], ao, 0, 0, 0);
                ai = __builtin_amdgcn_mfma_f32_16x16x32_bf16(a2, Bf[0][2], ai, 0, 0, 0);
                af = __builtin_amdgcn_mfma_f32_16x16x32_bf16(a2, Bf[1][2], af, 0, 0, 0);
                ag = __builtin_amdgcn_mfma_f32_16x16x32_bf16(a2, Bf[2][2], ag, 0, 0, 0);
                ao = __builtin_amdgcn_mfma_f32_16x16x32_bf16(a2, Bf[3][2], ao, 0, 0, 0);

                #pragma unroll
                for (int r = 0; r < 4; ++r) {
                    const float iv = sigm (ai[r] + bias[0]);
                    const float fv = sigm (af[r] + bias[1]);
                    const float gv = tanh_(ag[r] + bias[2]);
                    const float ov = sigm (ao[r] + bias[3]);
                    cc[r] = fv * cc[r] + iv * gv;
                    const float hv = ov * tanh_(cc[r]);
                    const unsigned short hb = f2bf(hv);
                    const int br = q * 4 + r;          // batch row (C/D layout)
                    A0[(t + 1) & 1][br][jc] = hb;      // next step's recurrent input
                    A1[t & 1][br][jc]       = hb;      // layer1's input at step t
                }
                if (dox) {
                    unsigned long long pk =
                        (unsigned long long)f2bf(xv.x)        |
                        ((unsigned long long)f2bf(xv.y) << 16) |
                        ((unsigned long long)f2bf(xv.z) << 32) |
                        ((unsigned long long)f2bf(xv.w) << 48);
                    *(unsigned long long*)&A0[(t + 1) & 1][xrow][64 + xh * 4] = pk;
                }
            }
        } else {
            const int t1 = it - 1;
            if (t1 >= 0) {
                const unsigned short* Ar = &A1[t1 & 1][ln][0];
                const short8 a0 = *(const short8*)(Ar + 0 * 32 + q * 8);
                const short8 a1 = *(const short8*)(Ar + 1 * 32 + q * 8);
                const short8 a2 = *(const short8*)(Ar + 2 * 32 + q * 8);
                const short8 a3 = *(const short8*)(Ar + 3 * 32 + q * 8);

                f32x4 ai = {0.f,0.f,0.f,0.f}, af = ai, ag = ai, ao = ai;
                ai = __builtin_amdgcn_mfma_f32_16x16x32_bf16(a0, Bf[0][0], ai, 0, 0, 0);
                af = __builtin_amdgcn_mfma_f32_16x16x32_bf16(a0, Bf[1][0], af, 0, 0, 0);
                ag = __builtin_amdgcn_mfma_f32_16x16x32_bf16(a0, Bf[2][0], ag, 0, 0, 0);
                ao = __builtin_amdgcn_mfma_f32_16x16x32_bf16(a0, Bf[3][0], ao, 0, 0, 0);
                ai = __builtin_amdgcn_mfma_f32_16x16x32_bf16(a1, Bf[0][1], ai, 0, 0, 0);
                af = __builtin_amdgcn_mfma_f32_16x16x32_bf16(a1, Bf[1][1], af, 0, 0, 0);
                ag = __builtin_amdgcn_mfma_f32_16x16x32_bf16(a1, Bf[2][1], ag, 0, 0, 0);
                ao = __builtin_amdgcn_mfma_f32_16x16x32_bf16(a1, Bf[3][1], ao, 0, 0, 0);
                ai = __builtin_amdgcn_mfma_f32_16x16x32_bf16(a2, Bf[0][2], ai, 0, 0, 0);
                af = __builtin_amdgcn_mfma_f32_16x16x32_bf16(a2, Bf[1][2], af, 0, 0, 0);
                ag = __builtin_amdgcn_mfma_f32_16x16x32_bf16(a2, Bf[2][2], ag, 0, 0, 0);
                ao = __builtin_amdgcn_mfma_f32_16x16x32_bf16(a2, Bf[3][2], ao, 0, 0, 0);
                ai = __builtin_amdgcn_mfma_f32_16x16x32_bf16(a3, Bf[0][3], ai, 0, 0, 0);
                af = __builtin_amdgcn_mfma_f32_16x16x32_bf16(a3, Bf[1][3], af, 0, 0, 0);
                ag = __builtin_amdgcn_mfma_f32_16x16x32_bf16(a3, Bf[2][3], ag, 0, 0, 0);
                ao = __builtin_amdgcn_mfma_f32_16x16x32_bf16(a3, Bf[3][3], ao, 0, 0, 0);

                #pragma unroll
                for (int r = 0; r < 4; ++r) {
                    const float iv = sigm (ai[r] + bias[0]);
                    const float fv = sigm (af[r] + bias[1]);
                    const float gv = tanh_(ag[r] + bias[2]);
                    const float ov = sigm (ao[r] + bias[3]);
                    cc[r] = fv * cc[r] + iv * gv;
                    const float hv = ov * tanh_(cc[r]);
                    const int br = q * 4 + r;
                    A1[(t1 + 1) & 1][br][64 + jc] = f2bf(hv);  // h1 for next step
                }
            }
        }
        __syncthreads();
    }

    // Final FC: h1_{T-1} sits in A1[(T-1+1)&1 = 0] cols 64..127
    if (tid < BSL) {
        float s = bfc[0];
        #pragma unroll 8
        for (int j = 0; j < 64; ++j)
            s += bf2f(A1[0][tid][64 + j]) * Wfc[j];
        out[rb + tid] = s;
    }
}

extern "C" void kernel_launch(void* const* d_in, const int* in_sizes, int n_in,
                              void* d_out, int out_size, void* d_ws, size_t ws_size,
                              hipStream_t stream) {
    const float* x    = (const float*)d_in[0];
    const float* Wih0 = (const float*)d_in[1];
    const float* Whh0 = (const float*)d_in[2];
    const float* bih0 = (const float*)d_in[3];
    const float* bhh0 = (const float*)d_in[4];
    const float* Wih1 = (const float*)d_in[5];
    const float* Whh1 = (const float*)d_in[6];
    const float* bih1 = (const float*)d_in[7];
    const float* bhh1 = (const float*)d_in[8];
    const float* Wfc  = (const float*)d_in[9];
    const float* bfc  = (const float*)d_in[10];
    float* out = (float*)d_out;

    dim3 grid(BTOT / BSL);   // 256 blocks = 1 per CU
    dim3 block(512);         // 8 waves: 4 layer-0 + 4 layer-1 (pipelined)
    lstm2_fused<<<grid, block, 0, stream>>>(x, Wih0, Whh0, bih0, bhh0,
                                            Wih1, Whh1, bih1, bhh1, Wfc, bfc, out);
}

// Round 2
// 579.644 us; speedup vs baseline: 3.4889x; 3.4889x over previous
//
#include <hip/hip_runtime.h>

// Problem constants (fixed by the reference)
#define BTOT 4096
#define TB   512      // T
#define BD   8        // D (input dim)
#define BSL  16       // batch rows per block
#define K0   96       // layer0 A logical K: [h0(64) | x(8) | pad(24)]
#define K0E  104      // padded LDS row stride (elements) -> 208 B, 16B-aligned, breaks 128B bank wrap
#define K1   128      // layer1 A logical K: [h0_t(64) | h1_prev(64)]
#define K1E  136      // padded LDS row stride -> 272 B

typedef __attribute__((ext_vector_type(8))) short  short8;  // 8 bf16 = 4 VGPR (MFMA A/B frag)
typedef __attribute__((ext_vector_type(4))) float  f32x4;   // MFMA C/D frag

static __device__ __forceinline__ unsigned short f2bf(float f) {
    unsigned u = __float_as_uint(f);
    u += 0x7fffu + ((u >> 16) & 1u);        // round-to-nearest-even
    return (unsigned short)(u >> 16);
}
static __device__ __forceinline__ float bf2f(unsigned short h) {
    return __uint_as_float(((unsigned)h) << 16);
}
// sigmoid(x) = 1/(1+2^(-x*log2e));  exp2 overflow -> inf -> rcp -> 0 (safe, NaN-free)
static __device__ __forceinline__ float sigm(float x) {
    float e = __builtin_amdgcn_exp2f(-1.44269504f * x);
    return __builtin_amdgcn_rcpf(1.0f + e);
}
// tanh(x) = 1 - 2/(1+2^(2x*log2e))
static __device__ __forceinline__ float tanh_(float x) {
    float e = __builtin_amdgcn_exp2f(2.88539008f * x);
    return 1.0f - 2.0f * __builtin_amdgcn_rcpf(1.0f + e);
}

__global__ __launch_bounds__(512, 2) void lstm2_fused(
    const float* __restrict__ x,
    const float* __restrict__ Wih0, const float* __restrict__ Whh0,
    const float* __restrict__ bih0, const float* __restrict__ bhh0,
    const float* __restrict__ Wih1, const float* __restrict__ Whh1,
    const float* __restrict__ bih1, const float* __restrict__ bhh1,
    const float* __restrict__ Wfc,  const float* __restrict__ bfc,
    float* __restrict__ out)
{
    // Double-buffered (by step parity) bf16 activation tiles.
    // Row strides padded (K0E/K1E) so row-stride mod 128B != 0 -> no 8-way
    // bank conflicts on the per-step h stores / A-frag reads.
    __shared__ __align__(16) unsigned short A0[2][BSL][K0E];
    __shared__ __align__(16) unsigned short A1[2][BSL][K1E];

    const int tid  = threadIdx.x;
    const int wid  = tid >> 6;
    const int lane = tid & 63;
    const int q    = lane >> 4;          // quad (k-chunk for A/B frags, row group for C/D)
    const int ln   = lane & 15;          // A row (m) / B col (n) / C col
    const int rb   = blockIdx.x * BSL;   // first batch row of this block

    const bool L1w = (wid >= 4);         // waves 4..7 = layer 1; waves 0..3 = layer 0
    const int  g   = L1w ? (wid - 4) : wid;
    const int  jc  = g * 16 + ln;        // hidden col (0..63) this lane owns for all 4 gates

    // ---- Weight (B-operand) fragments -> registers, bf16, once ----
    // CRITICAL: all loops fully unrolled with CONSTANT bounds so Bf[][] is
    // never dynamically indexed -> SROA keeps it in VGPRs (round-1 bug:
    // runtime trip count demoted Bf to scratch -> 738 MB HBM traffic).
    // B frag layout: lane holds B[k = ki*32 + q*8 + j][n].
    short8 Bf[4][4];                     // [gate][k_iter]; L0 uses k_iter 0..2
    #pragma unroll
    for (int G = 0; G < 4; ++G) {
        const int n = G * 64 + jc;       // gate output column (i,f,g,o blocks of 64)
        #pragma unroll
        for (int ki = 0; ki < 4; ++ki) {
            union { unsigned short u[8]; short8 v; } t;
            #pragma unroll
            for (int j = 0; j < 8; ++j) {
                const int k = ki * 32 + q * 8 + j;
                float w = 0.0f;
                if (!L1w) {
                    if (ki < 3) {        // compile-time after unroll
                        if (k < 64)      w = Whh0[n * 64 + k];          // recurrent
                        else if (k < 72) w = Wih0[n * 8 + (k - 64)];    // input proj (D=8)
                    }
                } else {
                    if (k < 64)          w = Wih1[n * 64 + k];          // from h0_t
                    else                 w = Whh1[n * 64 + (k - 64)];   // recurrent
                }
                t.u[j] = f2bf(w);
            }
            Bf[G][ki] = t.v;
        }
    }
    float bias[4];
    #pragma unroll
    for (int G = 0; G < 4; ++G) {
        const int n = G * 64 + jc;
        bias[G] = L1w ? (bih1[n] + bhh1[n]) : (bih0[n] + bhh0[n]);
    }

    // ---- Zero LDS (h_{-1}=0, pad regions must be exactly 0.0) ----
    {
        unsigned short* p0 = &A0[0][0][0];
        for (int i = tid; i < 2 * BSL * K0E; i += 512) p0[i] = 0;
        unsigned short* p1 = &A1[0][0][0];
        for (int i = tid; i < 2 * BSL * K1E; i += 512) p1[i] = 0;
    }
    __syncthreads();
    // ---- x_0 -> A0[0] x-region ----
    if (!L1w && lane < 8) {
        const int xrow = g * 4 + (lane >> 1), xh = lane & 1;
        const float4 v = *(const float4*)(x + ((size_t)(rb + xrow) * TB) * BD + xh * 4);
        unsigned long long pk =
            (unsigned long long)f2bf(v.x)        |
            ((unsigned long long)f2bf(v.y) << 16) |
            ((unsigned long long)f2bf(v.z) << 32) |
            ((unsigned long long)f2bf(v.w) << 48);
        *(unsigned long long*)&A0[0][xrow][64 + xh * 4] = pk;
    }
    __syncthreads();

    float cc[4] = {0.f, 0.f, 0.f, 0.f};  // fp32 cell state, never rounded

    // Pipeline: interval `it`: L0 computes step t=it, L1 computes step t1=it-1.
    for (int it = 0; it <= TB; ++it) {
        if (!L1w) {
            const int t = it;
            if (t < TB) {
                // Prefetch x_{t+1} early (hidden behind MFMA+gates)
                float4 xv;
                const bool dox = (lane < 8) && (t + 1 < TB);
                const int xrow = g * 4 + (lane >> 1), xh = lane & 1;
                if (dox)
                    xv = *(const float4*)(x + ((size_t)(rb + xrow) * TB + (t + 1)) * BD + xh * 4);

                const unsigned short* Ar = &A0[t & 1][ln][0];
                const short8 a0 = *(const short8*)(Ar + 0 * 32 + q * 8);
                const short8 a1 = *(const short8*)(Ar + 1 * 32 + q * 8);
                const short8 a2 = *(const short8*)(Ar + 2 * 32 + q * 8);

                f32x4 ai = {0.f,0.f,0.f,0.f}, af = ai, ag = ai, ao = ai;
                ai = __builtin_amdgcn_mfma_f32_16x16x32_bf16(a0, Bf[0][0], ai, 0, 0, 0);
                af = __builtin_amdgcn_mfma_f32_16x16x32_bf16(a0, Bf[1][0], af, 0, 0, 0);
                ag = __builtin_amdgcn_mfma_f32_16x16x32_bf16(a0, Bf[2][0], ag, 0, 0, 0);
                ao = __builtin_amdgcn_mfma_f32_16x16x32_bf16(a0, Bf[3][0], ao, 0, 0, 0);
                ai = __builtin_amdgcn_mfma_f32_16x16x32_bf16(a1, Bf[0][1], ai, 0, 0, 0);
                af = __builtin_amdgcn_mfma_f32_16x16x32_bf16(a1, Bf[1][1], af, 0, 0, 0);
                ag = __builtin_amdgcn_mfma_f32_16x16x32_bf16(a1, Bf[2][1], ag, 0, 0, 0);
                ao = __builtin_amdgcn_mfma_f32_16x16x32_bf16(a1, Bf[3][1], ao, 0, 0, 0);
                ai = __builtin_amdgcn_mfma_f32_16x16x32_bf16(a2, Bf[0][2], ai, 0, 0, 0);
                af = __builtin_amdgcn_mfma_f32_16x16x32_bf16(a2, Bf[1][2], af, 0, 0, 0);
                ag = __builtin_amdgcn_mfma_f32_16x16x32_bf16(a2, Bf[2][2], ag, 0, 0, 0);
                ao = __builtin_amdgcn_mfma_f32_16x16x32_bf16(a2, Bf[3][2], ao, 0, 0, 0);

                #pragma unroll
                for (int r = 0; r < 4; ++r) {
                    const float iv = sigm (ai[r] + bias[0]);
                    const float fv = sigm (af[r] + bias[1]);
                    const float gv = tanh_(ag[r] + bias[2]);
                    const float ov = sigm (ao[r] + bias[3]);
                    cc[r] = fv * cc[r] + iv * gv;
                    const float hv = ov * tanh_(cc[r]);
                    const unsigned short hb = f2bf(hv);
                    const int br = q * 4 + r;          // batch row (C/D layout)
                    A0[(t + 1) & 1][br][jc] = hb;      // next step's recurrent input
                    A1[t & 1][br][jc]       = hb;      // layer1's input at step t
                }
                if (dox) {
                    unsigned long long pk =
                        (unsigned long long)f2bf(xv.x)        |
                        ((unsigned long long)f2bf(xv.y) << 16) |
                        ((unsigned long long)f2bf(xv.z) << 32) |
                        ((unsigned long long)f2bf(xv.w) << 48);
                    *(unsigned long long*)&A0[(t + 1) & 1][xrow][64 + xh * 4] = pk;
                }
            }
        } else {
            const int t1 = it - 1;
            if (t1 >= 0) {
                const unsigned short* Ar = &A1[t1 & 1][ln][0];
                const short8 a0 = *(const short8*)(Ar + 0 * 32 + q * 8);
                const short8 a1 = *(const short8*)(Ar + 1 * 32 + q * 8);
                const short8 a2 = *(const short8*)(Ar + 2 * 32 + q * 8);
                const short8 a3 = *(const short8*)(Ar + 3 * 32 + q * 8);

                f32x4 ai = {0.f,0.f,0.f,0.f}, af = ai, ag = ai, ao = ai;
                ai = __builtin_amdgcn_mfma_f32_16x16x32_bf16(a0, Bf[0][0], ai, 0, 0, 0);
                af = __builtin_amdgcn_mfma_f32_16x16x32_bf16(a0, Bf[1][0], af, 0, 0, 0);
                ag = __builtin_amdgcn_mfma_f32_16x16x32_bf16(a0, Bf[2][0], ag, 0, 0, 0);
                ao = __builtin_amdgcn_mfma_f32_16x16x32_bf16(a0, Bf[3][0], ao, 0, 0, 0);
                ai = __builtin_amdgcn_mfma_f32_16x16x32_bf16(a1, Bf[0][1], ai, 0, 0, 0);
                af = __builtin_amdgcn_mfma_f32_16x16x32_bf16(a1, Bf[1][1], af, 0, 0, 0);
                ag = __builtin_amdgcn_mfma_f32_16x16x32_bf16(a1, Bf[2][1], ag, 0, 0, 0);
                ao = __builtin_amdgcn_mfma_f32_16x16x32_bf16(a1, Bf[3][1], ao, 0, 0, 0);
                ai = __builtin_amdgcn_mfma_f32_16x16x32_bf16(a2, Bf[0][2], ai, 0, 0, 0);
                af = __builtin_amdgcn_mfma_f32_16x16x32_bf16(a2, Bf[1][2], af, 0, 0, 0);
                ag = __builtin_amdgcn_mfma_f32_16x16x32_bf16(a2, Bf[2][2], ag, 0, 0, 0);
                ao = __builtin_amdgcn_mfma_f32_16x16x32_bf16(a2, Bf[3][2], ao, 0, 0, 0);
                ai = __builtin_amdgcn_mfma_f32_16x16x32_bf16(a3, Bf[0][3], ai, 0, 0, 0);
                af = __builtin_amdgcn_mfma_f32_16x16x32_bf16(a3, Bf[1][3], af, 0, 0, 0);
                ag = __builtin_amdgcn_mfma_f32_16x16x32_bf16(a3, Bf[2][3], ag, 0, 0, 0);
                ao = __builtin_amdgcn_mfma_f32_16x16x32_bf16(a3, Bf[3][3], ao, 0, 0, 0);

                #pragma unroll
                for (int r = 0; r < 4; ++r) {
                    const float iv = sigm (ai[r] + bias[0]);
                    const float fv = sigm (af[r] + bias[1]);
                    const float gv = tanh_(ag[r] + bias[2]);
                    const float ov = sigm (ao[r] + bias[3]);
                    cc[r] = fv * cc[r] + iv * gv;
                    const float hv = ov * tanh_(cc[r]);
                    const int br = q * 4 + r;
                    A1[(t1 + 1) & 1][br][64 + jc] = f2bf(hv);  // h1 for next step
                }
            }
        }
        __syncthreads();
    }

    // Final FC: h1_{T-1} sits in A1[(T-1+1)&1 = 0] cols 64..127
    if (tid < BSL) {
        float s = bfc[0];
        #pragma unroll 8
        for (int j = 0; j < 64; ++j)
            s += bf2f(A1[0][tid][64 + j]) * Wfc[j];
        out[rb + tid] = s;
    }
}

extern "C" void kernel_launch(void* const* d_in, const int* in_sizes, int n_in,
                              void* d_out, int out_size, void* d_ws, size_t ws_size,
                              hipStream_t stream) {
    const float* x    = (const float*)d_in[0];
    const float* Wih0 = (const float*)d_in[1];
    const float* Whh0 = (const float*)d_in[2];
    const float* bih0 = (const float*)d_in[3];
    const float* bhh0 = (const float*)d_in[4];
    const float* Wih1 = (const float*)d_in[5];
    const float* Whh1 = (const float*)d_in[6];
    const float* bih1 = (const float*)d_in[7];
    const float* bhh1 = (const float*)d_in[8];
    const float* Wfc  = (const float*)d_in[9];
    const float* bfc  = (const float*)d_in[10];
    float* out = (float*)d_out;

    dim3 grid(BTOT / BSL);   // 256 blocks = 1 per CU
    dim3 block(512);         // 8 waves: 4 layer-0 + 4 layer-1 (pipelined)
    lstm2_fused<<<grid, block, 0, stream>>>(x, Wih0, Whh0, bih0, bhh0,
                                            Wih1, Whh1, bih1, bhh1, Wfc, bfc, out);
}